// Round 15
// baseline (397.756 us; speedup 1.0000x reference)
//
#include <hip/hip_runtime.h>

typedef __attribute__((ext_vector_type(8))) short short8;
typedef __attribute__((ext_vector_type(4))) float f32x4;
typedef unsigned short u16;

#define T_SEQ 2048
#define C_DIM 2048

static __device__ __forceinline__ u16 f2bf(float f){
  unsigned u = __float_as_uint(f);
  u = (u + 0x7fffu + ((u >> 16) & 1u)) >> 16;
  return (u16)u;
}

// merged f32->bf16 convert for x, w_attn, w_proj
__global__ void cvt3_kernel(const float* __restrict__ x,
                            const float* __restrict__ wa,
                            const float* __restrict__ wp,
                            u16* __restrict__ xb, u16* __restrict__ wab,
                            u16* __restrict__ wpb){
  int idx = blockIdx.x * blockDim.x + threadIdx.x;
  int stride = gridDim.x * blockDim.x;
  for (int i = idx; i < 6291456; i += stride){
    const float* src; u16* dst; int j;
    if (i < 2097152){ src = x;  dst = xb;  j = i; }
    else if (i < 5242880){ src = wa; dst = wab; j = i - 2097152; }
    else { src = wp; dst = wpb; j = i - 5242880; }
    float4 v = ((const float4*)src)[j];
    ushort4 o;
    o.x = f2bf(v.x); o.y = f2bf(v.y); o.z = f2bf(v.z); o.w = f2bf(v.w);
    ((ushort4*)dst)[j] = o;
  }
}

__device__ __forceinline__ void gl_lds16(const void* g, void* l){
  __builtin_amdgcn_global_load_lds(
      (const __attribute__((address_space(1))) unsigned int*)g,
      (__attribute__((address_space(3))) unsigned int*)l,
      16, 0, 0);
}

// ------------- 128x128 BK=64 2-phase counted-vmcnt GEMM, 2 blocks/CU --------
// (round-14 verified kernel, unchanged)
template<int MODE, typename OUT>
__global__ __launch_bounds__(256, 2) void gemm256(const u16* __restrict__ A,
                                                  const u16* __restrict__ B,
                                                  OUT* __restrict__ C,
                                                  u16* __restrict__ VT,
                                                  int M, int N, int K){
  __shared__ __align__(16) u16 lA[2][128*64];   // 32 KB
  __shared__ __align__(16) u16 lB[2][128*64];   // 32 KB
  const int tid  = threadIdx.x;
  const int lane = tid & 63;
  const int r16  = lane & 15;
  const int g4   = lane >> 4;
  const int wave = tid >> 6;                 // 0..3
  const int wm = wave >> 1, wn = wave & 1;   // 2M x 2N

  const int nwg = gridDim.x * gridDim.y;
  const int idl = blockIdx.y * gridDim.x + blockIdx.x;
  const int wg  = (idl & 7) * (nwg >> 3) + (idl >> 3);
  const int bx  = wg / gridDim.y, by = wg % gridDim.y;
  const int m0 = by * 128, n0 = bx * 128;

  f32x4 acc[4][4] = {};
  const int nt = K >> 6;

  auto stA = [&](int b, int t){
    #pragma unroll
    for (int c=0;c<4;c++){
      const int row0 = wave*32 + c*8;
      const int row  = row0 + (lane>>3);
      const int cole = (((lane&7) ^ (row&7)) << 3);
      gl_lds16(&A[(size_t)(m0+row)*K + t*64 + cole], &lA[b][row0*64]);
    }
  };
  auto stB2 = [&](int b, int t, int half){
    #pragma unroll
    for (int c=0;c<2;c++){
      const int row0 = (wave>>1)*64 + half*32 + (wave&1)*16 + c*8;
      const int row  = row0 + (lane>>3);
      const int cole = (((lane&7) ^ (row&7)) << 3);
      gl_lds16(&B[(size_t)(n0+row)*K + t*64 + cole], &lB[b][row0*64]);
    }
  };
  auto rdA = [&](short8 (&af)[4][2], int b){
    #pragma unroll
    for (int i=0;i<4;i++){
      const int R = wm*64 + i*16 + r16;
      #pragma unroll
      for (int ks=0;ks<2;ks++)
        af[i][ks] = *(const short8*)&lA[b][R*64 + ((g4*8 + ks*32) ^ ((R&7)<<3))];
    }
  };
  auto rdB = [&](short8 (&bf)[2][2], int b, int half){
    #pragma unroll
    for (int j=0;j<2;j++){
      const int R = wn*64 + half*32 + j*16 + r16;
      #pragma unroll
      for (int ks=0;ks<2;ks++)
        bf[j][ks] = *(const short8*)&lB[b][R*64 + ((g4*8 + ks*32) ^ ((R&7)<<3))];
    }
  };

  stA(0,0); stB2(0,0,0); stB2(0,0,1);
  asm volatile("s_waitcnt vmcnt(2)" ::: "memory");
  __builtin_amdgcn_s_barrier();
  asm volatile("" ::: "memory");

  for (int t = 0; t < nt; ++t){
    const int cb = t & 1, nb = cb ^ 1;
    const bool more = (t + 1 < nt);
    short8 af[4][2], bf[2][2];

    rdA(af, cb); rdB(bf, cb, 0);
    if (more){
      stA(nb, t+1); stB2(nb, t+1, 0);
      asm volatile("s_waitcnt vmcnt(6)" ::: "memory");
    } else {
      asm volatile("s_waitcnt vmcnt(0)" ::: "memory");
    }
    __builtin_amdgcn_s_barrier();
    asm volatile("s_waitcnt lgkmcnt(0)" ::: "memory");
    __builtin_amdgcn_sched_barrier(0);
    __builtin_amdgcn_s_setprio(1);
    #pragma unroll
    for (int i=0;i<4;i++)
      #pragma unroll
      for (int j=0;j<2;j++)
        #pragma unroll
        for (int ks=0;ks<2;ks++)
          acc[i][j] = __builtin_amdgcn_mfma_f32_16x16x32_bf16(af[i][ks], bf[j][ks], acc[i][j], 0,0,0);
    __builtin_amdgcn_s_setprio(0);
    __builtin_amdgcn_s_barrier();
    asm volatile("" ::: "memory");

    rdB(bf, cb, 1);
    if (more){
      stB2(nb, t+1, 1);
      asm volatile("s_waitcnt vmcnt(2)" ::: "memory");
    }
    __builtin_amdgcn_s_barrier();
    asm volatile("s_waitcnt lgkmcnt(0)" ::: "memory");
    __builtin_amdgcn_sched_barrier(0);
    __builtin_amdgcn_s_setprio(1);
    #pragma unroll
    for (int i=0;i<4;i++)
      #pragma unroll
      for (int j=0;j<2;j++)
        #pragma unroll
        for (int ks=0;ks<2;ks++)
          acc[i][2+j] = __builtin_amdgcn_mfma_f32_16x16x32_bf16(af[i][ks], bf[j][ks], acc[i][2+j], 0,0,0);
    __builtin_amdgcn_s_setprio(0);
    __builtin_amdgcn_s_barrier();
    asm volatile("" ::: "memory");
  }

  if (MODE == 1 && n0 >= 4096){
    #pragma unroll
    for (int i=0;i<4;i++){
      const int m = m0 + wm*64 + i*16 + g4*4;
      const int bb = m >> 11, tt = m & 2047;
      #pragma unroll
      for (int j=0;j<4;j++){
        const int cv = n0 + wn*64 + j*16 + r16 - 4096;
        const int h = cv >> 7, dl = cv & 127;
        ushort4 pack;
        pack.x = f2bf(acc[i][j][0]); pack.y = f2bf(acc[i][j][1]);
        pack.z = f2bf(acc[i][j][2]); pack.w = f2bf(acc[i][j][3]);
        *(ushort4*)&VT[(size_t)((bb<<4) + h)*262144 + (size_t)dl*2048 + tt] = pack;
      }
    }
  } else {
    const int ldc = (MODE == 1) ? 4096 : N;
    #pragma unroll
    for (int i=0;i<4;i++){
      const int row = m0 + wm*64 + i*16 + g4*4;
      #pragma unroll
      for (int j=0;j<4;j++){
        const int col = n0 + wn*64 + j*16 + r16;
        #pragma unroll
        for (int r=0;r<4;r++){
          float v = acc[i][j][r];
          if constexpr (sizeof(OUT)==2) C[(size_t)(row+r)*ldc + col] = (OUT)f2bf(v);
          else                          C[(size_t)(row+r)*ldc + col] = (OUT)v;
        }
      }
    }
  }
}

// ---------------- Balanced-causal flash attention ---------------------------
// Each block owns TWO 64-row q-tiles of one head: a and b=31-a. Per wave:
// 16 rows of tile-a (frag i=0) + 16 rows of tile-b (i=1). KV loop t=0..b;
// i=0 active iff t<=a -> every block does exactly 33 tile-units of MFMA+
// softmax (constant work, balanced across all 512 blocks / 2-per-CU).
// Masks: i=0 at t==a, i=1 at t==b (block-uniform). Defer-max with LOCAL
// pre-check (skips the 4-shfl max reduce on the common path; equivalent
// condition since mrow is row-uniform).
__global__ __launch_bounds__(256) void attn_kernel(const u16* __restrict__ qk,
                                                   const u16* __restrict__ vt,
                                                   u16* __restrict__ y){
  __shared__ __align__(16) u16 Kl[2][64*128];
  __shared__ __align__(16) u16 Vl[2][128*64];
  __shared__ __align__(16) u16 Pl[4][32*64];

  const int tid = threadIdx.x, lane = tid & 63, wave = tid >> 6;
  const int r16 = lane & 15, g4 = lane >> 4;

  const int id = blockIdx.x;            // 0..511
  const int xk = id & 7,  kk = id >> 3;
  const int bh = 4*xk + (kk & 3);       // XCD-local heads
  const int a  = kk >> 2;               // 0..15
  const int bq = 31 - a;

  const int bb = bh >> 4, h = bh & 15;
  const int qcol = h*128, kcol = 2048 + h*128;
  const u16* vhead = vt + (size_t)bh * 262144;
  const float scale = 0.08838834764831845f;

  const int qbase[2] = { a*64, bq*64 };

  short8 qf[2][4];
  #pragma unroll
  for (int i=0;i<2;i++){
    const u16* qp = qk + (size_t)(bb*T_SEQ + qbase[i] + wave*16 + r16)*4096 + qcol;
    #pragma unroll
    for (int c=0;c<4;c++) qf[i][c] = *(const short8*)&qp[g4*8 + c*32];
  }

  float mrow[2][4], lrow[2][4];
  #pragma unroll
  for (int i=0;i<2;i++)
    #pragma unroll
    for (int r=0;r<4;r++){ mrow[i][r] = -1e30f; lrow[i][r] = 0.f; }
  f32x4 o[2][8] = {};

  const int nt = bq + 1;

  auto stage = [&](int sbuf, int t){
    const size_t kbase = (size_t)(bb*T_SEQ + t*64)*4096 + kcol;
    #pragma unroll
    for (int c=0;c<4;c++){
      const int row0 = wave*16 + c*4;
      const int row  = row0 + g4;
      gl_lds16(&qk[kbase + (size_t)row*4096 + ((r16*8) ^ ((row&7)<<3))],
               &Kl[sbuf][row0*128]);
    }
    const int t0 = t*64;
    #pragma unroll
    for (int c=0;c<4;c++){
      const int idx = wave*4 + c;
      const int d   = idx*8 + (lane>>3);
      const int j8  = (lane&7)*8;
      gl_lds16(&vhead[(size_t)d*2048 + t0 + (j8 ^ ((d&7)<<3))],
               &Vl[sbuf][idx*512]);
    }
  };

  stage(0, 0);
  int cur = 0;

  for (int t = 0; t < nt; ++t){
    __syncthreads();
    if (t + 1 < nt) stage(cur^1, t+1);
    const bool act0 = (t <= a);   // block-uniform

    float smat[2][4][4];
    #pragma unroll
    for (int cc=0;cc<4;cc++){
      const int krow = cc*16 + r16;
      const int sw = (krow & 7) << 3;
      short8 kf[4];
      #pragma unroll
      for (int dc=0;dc<4;dc++)
        kf[dc] = *(const short8*)&Kl[cur][krow*128 + ((g4*8 + dc*32) ^ sw)];
      {  // i=1 always active
        f32x4 sv = {0.f,0.f,0.f,0.f};
        #pragma unroll
        for (int dc=0;dc<4;dc++)
          sv = __builtin_amdgcn_mfma_f32_16x16x32_bf16(qf[1][dc], kf[dc], sv, 0,0,0);
        #pragma unroll
        for (int rr=0;rr<4;rr++) smat[1][cc][rr] = sv[rr] * scale;
      }
      if (act0){
        f32x4 sv = {0.f,0.f,0.f,0.f};
        #pragma unroll
        for (int dc=0;dc<4;dc++)
          sv = __builtin_amdgcn_mfma_f32_16x16x32_bf16(qf[0][dc], kf[dc], sv, 0,0,0);
        #pragma unroll
        for (int rr=0;rr<4;rr++) smat[0][cc][rr] = sv[rr] * scale;
      }
    }
    // diagonal masks (block-uniform branches)
    if (t == a){
      #pragma unroll
      for (int cc=0;cc<4;cc++){
        const int kvl = cc*16 + r16;
        #pragma unroll
        for (int rr=0;rr<4;rr++){
          const int qi = wave*16 + g4*4 + rr;
          if (kvl > qi) smat[0][cc][rr] = -1e30f;
        }
      }
    }
    if (t == bq){
      #pragma unroll
      for (int cc=0;cc<4;cc++){
        const int kvl = cc*16 + r16;
        #pragma unroll
        for (int rr=0;rr<4;rr++){
          const int qi = wave*16 + g4*4 + rr;
          if (kvl > qi) smat[1][cc][rr] = -1e30f;
        }
      }
    }

    // ---- defer-max softmax with local pre-check
    float lm[2][4];
    #pragma unroll
    for (int rr=0;rr<4;rr++)
      lm[1][rr] = fmaxf(fmaxf(smat[1][0][rr], smat[1][1][rr]),
                        fmaxf(smat[1][2][rr], smat[1][3][rr]));
    if (act0)
      #pragma unroll
      for (int rr=0;rr<4;rr++)
        lm[0][rr] = fmaxf(fmaxf(smat[0][0][rr], smat[0][1][rr]),
                          fmaxf(smat[0][2][rr], smat[0][3][rr]));
    bool need = false;
    #pragma unroll
    for (int rr=0;rr<4;rr++) need = need || (lm[1][rr] > mrow[1][rr] + 8.f);
    if (act0)
      #pragma unroll
      for (int rr=0;rr<4;rr++) need = need || (lm[0][rr] > mrow[0][rr] + 8.f);
    if (__any(need)){
      const int ihi = act0 ? 0 : 1;
      for (int i=1;i>=ihi;--i)
        #pragma unroll
        for (int rr=0;rr<4;rr++){
          float pmv = lm[i][rr];
          #pragma unroll
          for (int off=1; off<16; off<<=1) pmv = fmaxf(pmv, __shfl_xor(pmv, off, 64));
          const float mnew = fmaxf(mrow[i][rr], pmv);
          const float corr = __expf(mrow[i][rr] - mnew);
          mrow[i][rr] = mnew;
          lrow[i][rr] *= corr;
          #pragma unroll
          for (int n=0;n<8;n++) o[i][n][rr] *= corr;
        }
    }
    {
      const int ihi = act0 ? 0 : 1;
      for (int i=1;i>=ihi;--i)
        #pragma unroll
        for (int rr=0;rr<4;rr++){
          float s0 = 0.f;
          #pragma unroll
          for (int cc=0;cc<4;cc++){
            const float p = __expf(smat[i][cc][rr] - mrow[i][rr]);
            smat[i][cc][rr] = p;
            s0 += p;
          }
          #pragma unroll
          for (int off=1; off<16; off<<=1) s0 += __shfl_xor(s0, off, 64);
          lrow[i][rr] += s0;
        }
    }

    // ---- P -> LDS (active halves only)
    {
      const int ihi = act0 ? 0 : 1;
      for (int i=1;i>=ihi;--i)
        #pragma unroll
        for (int cc=0;cc<4;cc++)
          #pragma unroll
          for (int rr=0;rr<4;rr++){
            const int qr = i*16 + g4*4 + rr;
            Pl[wave][qr*64 + ((cc*16 + r16) ^ ((qr&7)<<3))] = f2bf(smat[i][cc][rr]);
          }
    }
    asm volatile("s_waitcnt lgkmcnt(0)" ::: "memory");

    short8 pf[2][2];
    {
      const int qr1 = 16 + r16;
      const int sw1 = (qr1 & 7) << 3;
      pf[1][0] = *(const short8*)&Pl[wave][qr1*64 + ((g4*8)      ^ sw1)];
      pf[1][1] = *(const short8*)&Pl[wave][qr1*64 + ((g4*8 + 32) ^ sw1)];
      if (act0){
        const int qr0 = r16;
        const int sw0 = (qr0 & 7) << 3;
        pf[0][0] = *(const short8*)&Pl[wave][qr0*64 + ((g4*8)      ^ sw0)];
        pf[0][1] = *(const short8*)&Pl[wave][qr0*64 + ((g4*8 + 32) ^ sw0)];
      }
    }
    #pragma unroll
    for (int n=0;n<8;n++){
      const int vr = n*16 + r16;
      const int sw = (vr & 7) << 3;
      short8 vf0 = *(const short8*)&Vl[cur][vr*64 + ((g4*8)      ^ sw)];
      short8 vf1 = *(const short8*)&Vl[cur][vr*64 + ((g4*8 + 32) ^ sw)];
      o[1][n] = __builtin_amdgcn_mfma_f32_16x16x32_bf16(pf[1][0], vf0, o[1][n], 0,0,0);
      o[1][n] = __builtin_amdgcn_mfma_f32_16x16x32_bf16(pf[1][1], vf1, o[1][n], 0,0,0);
      if (act0){
        o[0][n] = __builtin_amdgcn_mfma_f32_16x16x32_bf16(pf[0][0], vf0, o[0][n], 0,0,0);
        o[0][n] = __builtin_amdgcn_mfma_f32_16x16x32_bf16(pf[0][1], vf1, o[0][n], 0,0,0);
      }
    }
    cur ^= 1;
  }

  #pragma unroll
  for (int i=0;i<2;i++){
    const size_t yr0 = (size_t)(bb*T_SEQ + qbase[i] + wave*16 + g4*4) * C_DIM + h*128;
    #pragma unroll
    for (int n=0;n<8;n++)
      #pragma unroll
      for (int rr=0;rr<4;rr++){
        const float v = o[i][n][rr] / lrow[i][rr];
        y[yr0 + (size_t)rr*C_DIM + n*16 + r16] = f2bf(v);
      }
  }
}

extern "C" void kernel_launch(void* const* d_in, const int* in_sizes, int n_in,
                              void* d_out, int out_size, void* d_ws, size_t ws_size,
                              hipStream_t stream){
  const float* x  = (const float*)d_in[0];
  const float* wa = (const float*)d_in[1];
  const float* wp = (const float*)d_in[2];
  float* out = (float*)d_out;

  u16* ws  = (u16*)d_ws;
  u16* xb  = ws;                 //  8,388,608 elems (x bf16) — reused as yb later
  u16* wab = xb  + 8388608;      // 12,582,912 elems (w_attn bf16)
  u16* wpb = wab + 12582912;     //  4,194,304 elems (w_proj bf16)
  u16* qk  = wpb + 4194304;      // 16,777,216 elems ([4096][4096] Q|K)
  u16* vt  = qk  + 16777216;     //  8,388,608 elems ([32][128][2048] V^T)
  u16* yb  = xb;                 // alias: x dead after GEMM1

  hipLaunchKernelGGL(cvt3_kernel, dim3(2048), dim3(256), 0, stream,
                     x, wa, wp, xb, wab, wpb);

  // qkv projection: grid 48 n-tiles(128) x 32 m-tiles(128) = 1536 = 3 rounds @ 2/CU
  hipLaunchKernelGGL((gemm256<1,u16>),   dim3(48,32), dim3(256), 0, stream,
                     xb, wab, qk, vt, 4096, 6144, 2048);
  hipLaunchKernelGGL(attn_kernel,        dim3(512),  dim3(256), 0, stream,
                     qk, vt, yb);
  // out projection: grid 16 x 32 = 512 = 1 round @ 2/CU
  hipLaunchKernelGGL((gemm256<0,float>), dim3(16,32), dim3(256), 0, stream,
                     yb, wpb, out, (u16*)nullptr, 4096, 2048, 2048);
}

// Round 16
// 299.540 us; speedup vs baseline: 1.3279x; 1.3279x over previous
//
#include <hip/hip_runtime.h>

typedef __attribute__((ext_vector_type(8))) short short8;
typedef __attribute__((ext_vector_type(4))) float f32x4;
typedef unsigned short u16;

#define T_SEQ 2048
#define C_DIM 2048

static __device__ __forceinline__ u16 f2bf(float f){
  unsigned u = __float_as_uint(f);
  u = (u + 0x7fffu + ((u >> 16) & 1u)) >> 16;
  return (u16)u;
}

// merged f32->bf16 convert for x, w_attn, w_proj
__global__ void cvt3_kernel(const float* __restrict__ x,
                            const float* __restrict__ wa,
                            const float* __restrict__ wp,
                            u16* __restrict__ xb, u16* __restrict__ wab,
                            u16* __restrict__ wpb){
  int idx = blockIdx.x * blockDim.x + threadIdx.x;
  int stride = gridDim.x * blockDim.x;
  for (int i = idx; i < 6291456; i += stride){
    const float* src; u16* dst; int j;
    if (i < 2097152){ src = x;  dst = xb;  j = i; }
    else if (i < 5242880){ src = wa; dst = wab; j = i - 2097152; }
    else { src = wp; dst = wpb; j = i - 5242880; }
    float4 v = ((const float4*)src)[j];
    ushort4 o;
    o.x = f2bf(v.x); o.y = f2bf(v.y); o.z = f2bf(v.z); o.w = f2bf(v.w);
    ((ushort4*)dst)[j] = o;
  }
}

__device__ __forceinline__ void gl_lds16(const void* g, void* l){
  __builtin_amdgcn_global_load_lds(
      (const __attribute__((address_space(1))) unsigned int*)g,
      (__attribute__((address_space(3))) unsigned int*)l,
      16, 0, 0);
}

// ------------- 128x128 BK=64 2-phase counted-vmcnt GEMM, 2 blocks/CU --------
// (round-14 verified kernel, unchanged)
template<int MODE, typename OUT>
__global__ __launch_bounds__(256, 2) void gemm256(const u16* __restrict__ A,
                                                  const u16* __restrict__ B,
                                                  OUT* __restrict__ C,
                                                  u16* __restrict__ VT,
                                                  int M, int N, int K){
  __shared__ __align__(16) u16 lA[2][128*64];   // 32 KB
  __shared__ __align__(16) u16 lB[2][128*64];   // 32 KB
  const int tid  = threadIdx.x;
  const int lane = tid & 63;
  const int r16  = lane & 15;
  const int g4   = lane >> 4;
  const int wave = tid >> 6;                 // 0..3
  const int wm = wave >> 1, wn = wave & 1;   // 2M x 2N

  const int nwg = gridDim.x * gridDim.y;
  const int idl = blockIdx.y * gridDim.x + blockIdx.x;
  const int wg  = (idl & 7) * (nwg >> 3) + (idl >> 3);
  const int bx  = wg / gridDim.y, by = wg % gridDim.y;
  const int m0 = by * 128, n0 = bx * 128;

  f32x4 acc[4][4] = {};
  const int nt = K >> 6;

  auto stA = [&](int b, int t){
    #pragma unroll
    for (int c=0;c<4;c++){
      const int row0 = wave*32 + c*8;
      const int row  = row0 + (lane>>3);
      const int cole = (((lane&7) ^ (row&7)) << 3);
      gl_lds16(&A[(size_t)(m0+row)*K + t*64 + cole], &lA[b][row0*64]);
    }
  };
  auto stB2 = [&](int b, int t, int half){
    #pragma unroll
    for (int c=0;c<2;c++){
      const int row0 = (wave>>1)*64 + half*32 + (wave&1)*16 + c*8;
      const int row  = row0 + (lane>>3);
      const int cole = (((lane&7) ^ (row&7)) << 3);
      gl_lds16(&B[(size_t)(n0+row)*K + t*64 + cole], &lB[b][row0*64]);
    }
  };
  auto rdA = [&](short8 (&af)[4][2], int b){
    #pragma unroll
    for (int i=0;i<4;i++){
      const int R = wm*64 + i*16 + r16;
      #pragma unroll
      for (int ks=0;ks<2;ks++)
        af[i][ks] = *(const short8*)&lA[b][R*64 + ((g4*8 + ks*32) ^ ((R&7)<<3))];
    }
  };
  auto rdB = [&](short8 (&bf)[2][2], int b, int half){
    #pragma unroll
    for (int j=0;j<2;j++){
      const int R = wn*64 + half*32 + j*16 + r16;
      #pragma unroll
      for (int ks=0;ks<2;ks++)
        bf[j][ks] = *(const short8*)&lB[b][R*64 + ((g4*8 + ks*32) ^ ((R&7)<<3))];
    }
  };

  stA(0,0); stB2(0,0,0); stB2(0,0,1);
  asm volatile("s_waitcnt vmcnt(2)" ::: "memory");
  __builtin_amdgcn_s_barrier();
  asm volatile("" ::: "memory");

  for (int t = 0; t < nt; ++t){
    const int cb = t & 1, nb = cb ^ 1;
    const bool more = (t + 1 < nt);
    short8 af[4][2], bf[2][2];

    rdA(af, cb); rdB(bf, cb, 0);
    if (more){
      stA(nb, t+1); stB2(nb, t+1, 0);
      asm volatile("s_waitcnt vmcnt(6)" ::: "memory");
    } else {
      asm volatile("s_waitcnt vmcnt(0)" ::: "memory");
    }
    __builtin_amdgcn_s_barrier();
    asm volatile("s_waitcnt lgkmcnt(0)" ::: "memory");
    __builtin_amdgcn_sched_barrier(0);
    __builtin_amdgcn_s_setprio(1);
    #pragma unroll
    for (int i=0;i<4;i++)
      #pragma unroll
      for (int j=0;j<2;j++)
        #pragma unroll
        for (int ks=0;ks<2;ks++)
          acc[i][j] = __builtin_amdgcn_mfma_f32_16x16x32_bf16(af[i][ks], bf[j][ks], acc[i][j], 0,0,0);
    __builtin_amdgcn_s_setprio(0);
    __builtin_amdgcn_s_barrier();
    asm volatile("" ::: "memory");

    rdB(bf, cb, 1);
    if (more){
      stB2(nb, t+1, 1);
      asm volatile("s_waitcnt vmcnt(2)" ::: "memory");
    }
    __builtin_amdgcn_s_barrier();
    asm volatile("s_waitcnt lgkmcnt(0)" ::: "memory");
    __builtin_amdgcn_sched_barrier(0);
    __builtin_amdgcn_s_setprio(1);
    #pragma unroll
    for (int i=0;i<4;i++)
      #pragma unroll
      for (int j=0;j<2;j++)
        #pragma unroll
        for (int ks=0;ks<2;ks++)
          acc[i][2+j] = __builtin_amdgcn_mfma_f32_16x16x32_bf16(af[i][ks], bf[j][ks], acc[i][2+j], 0,0,0);
    __builtin_amdgcn_s_setprio(0);
    __builtin_amdgcn_s_barrier();
    asm volatile("" ::: "memory");
  }

  if (MODE == 1 && n0 >= 4096){
    #pragma unroll
    for (int i=0;i<4;i++){
      const int m = m0 + wm*64 + i*16 + g4*4;
      const int bb = m >> 11, tt = m & 2047;
      #pragma unroll
      for (int j=0;j<4;j++){
        const int cv = n0 + wn*64 + j*16 + r16 - 4096;
        const int h = cv >> 7, dl = cv & 127;
        ushort4 pack;
        pack.x = f2bf(acc[i][j][0]); pack.y = f2bf(acc[i][j][1]);
        pack.z = f2bf(acc[i][j][2]); pack.w = f2bf(acc[i][j][3]);
        *(ushort4*)&VT[(size_t)((bb<<4) + h)*262144 + (size_t)dl*2048 + tt] = pack;
      }
    }
  } else {
    const int ldc = (MODE == 1) ? 4096 : N;
    #pragma unroll
    for (int i=0;i<4;i++){
      const int row = m0 + wm*64 + i*16 + g4*4;
      #pragma unroll
      for (int j=0;j<4;j++){
        const int col = n0 + wn*64 + j*16 + r16;
        #pragma unroll
        for (int r=0;r<4;r++){
          float v = acc[i][j][r];
          if constexpr (sizeof(OUT)==2) C[(size_t)(row+r)*ldc + col] = (OUT)f2bf(v);
          else                          C[(size_t)(row+r)*ldc + col] = (OUT)v;
        }
      }
    }
  }
}

// ---------------- Balanced-causal flash attention (static-index fix) --------
// Each block owns TWO 64-row q-tiles of one head: a and b=31-a. Per wave:
// 16 rows of tile-a (frag 0) + 16 rows of tile-b (frag 1). KV loop t=0..b;
// frag 0 active iff t<=a -> constant 33 tile-units per block.
// r15 lesson (rule #20): NO runtime-variable indexing of register arrays —
// every smat/o/mrow/lrow/pf access below uses compile-time indices; the
// act0-conditional work is expressed as static i=1 block + `if(act0)` i=0
// block.
__global__ __launch_bounds__(256) void attn_kernel(const u16* __restrict__ qk,
                                                   const u16* __restrict__ vt,
                                                   u16* __restrict__ y){
  __shared__ __align__(16) u16 Kl[2][64*128];
  __shared__ __align__(16) u16 Vl[2][128*64];
  __shared__ __align__(16) u16 Pl[4][32*64];

  const int tid = threadIdx.x, lane = tid & 63, wave = tid >> 6;
  const int r16 = lane & 15, g4 = lane >> 4;

  const int id = blockIdx.x;            // 0..511
  const int xk = id & 7,  kk = id >> 3;
  const int bh = 4*xk + (kk & 3);       // XCD-local heads
  const int a  = kk >> 2;               // 0..15
  const int bq = 31 - a;

  const int bb = bh >> 4, h = bh & 15;
  const int qcol = h*128, kcol = 2048 + h*128;
  const u16* vhead = vt + (size_t)bh * 262144;
  const float scale = 0.08838834764831845f;

  short8 qf0[4], qf1[4];
  {
    const u16* qp0 = qk + (size_t)(bb*T_SEQ + a*64  + wave*16 + r16)*4096 + qcol;
    const u16* qp1 = qk + (size_t)(bb*T_SEQ + bq*64 + wave*16 + r16)*4096 + qcol;
    #pragma unroll
    for (int c=0;c<4;c++){
      qf0[c] = *(const short8*)&qp0[g4*8 + c*32];
      qf1[c] = *(const short8*)&qp1[g4*8 + c*32];
    }
  }

  float m0r[4], m1r[4], l0r[4], l1r[4];
  #pragma unroll
  for (int r=0;r<4;r++){ m0r[r] = -1e30f; m1r[r] = -1e30f; l0r[r] = 0.f; l1r[r] = 0.f; }
  f32x4 o0[8] = {}, o1[8] = {};

  const int nt = bq + 1;

  auto stage = [&](int sbuf, int t){
    const size_t kbase = (size_t)(bb*T_SEQ + t*64)*4096 + kcol;
    #pragma unroll
    for (int c=0;c<4;c++){
      const int row0 = wave*16 + c*4;
      const int row  = row0 + g4;
      gl_lds16(&qk[kbase + (size_t)row*4096 + ((r16*8) ^ ((row&7)<<3))],
               &Kl[sbuf][row0*128]);
    }
    const int t0 = t*64;
    #pragma unroll
    for (int c=0;c<4;c++){
      const int idx = wave*4 + c;
      const int d   = idx*8 + (lane>>3);
      const int j8  = (lane&7)*8;
      gl_lds16(&vhead[(size_t)d*2048 + t0 + (j8 ^ ((d&7)<<3))],
               &Vl[sbuf][idx*512]);
    }
  };

  stage(0, 0);
  int cur = 0;

  for (int t = 0; t < nt; ++t){
    __syncthreads();
    if (t + 1 < nt) stage(cur^1, t+1);
    const bool act0 = (t <= a);   // block-uniform

    float s0m[4][4], s1m[4][4];
    #pragma unroll
    for (int cc=0;cc<4;cc++){
      const int krow = cc*16 + r16;
      const int sw = (krow & 7) << 3;
      short8 kf[4];
      #pragma unroll
      for (int dc=0;dc<4;dc++)
        kf[dc] = *(const short8*)&Kl[cur][krow*128 + ((g4*8 + dc*32) ^ sw)];
      {
        f32x4 sv = {0.f,0.f,0.f,0.f};
        #pragma unroll
        for (int dc=0;dc<4;dc++)
          sv = __builtin_amdgcn_mfma_f32_16x16x32_bf16(qf1[dc], kf[dc], sv, 0,0,0);
        #pragma unroll
        for (int rr=0;rr<4;rr++) s1m[cc][rr] = sv[rr] * scale;
      }
      if (act0){
        f32x4 sv = {0.f,0.f,0.f,0.f};
        #pragma unroll
        for (int dc=0;dc<4;dc++)
          sv = __builtin_amdgcn_mfma_f32_16x16x32_bf16(qf0[dc], kf[dc], sv, 0,0,0);
        #pragma unroll
        for (int rr=0;rr<4;rr++) s0m[cc][rr] = sv[rr] * scale;
      }
    }
    // diagonal masks (block-uniform branches)
    if (t == a){
      #pragma unroll
      for (int cc=0;cc<4;cc++){
        const int kvl = cc*16 + r16;
        #pragma unroll
        for (int rr=0;rr<4;rr++){
          const int qi = wave*16 + g4*4 + rr;
          if (kvl > qi) s0m[cc][rr] = -1e30f;
        }
      }
    }
    if (t == bq){
      #pragma unroll
      for (int cc=0;cc<4;cc++){
        const int kvl = cc*16 + r16;
        #pragma unroll
        for (int rr=0;rr<4;rr++){
          const int qi = wave*16 + g4*4 + rr;
          if (kvl > qi) s1m[cc][rr] = -1e30f;
        }
      }
    }

    // ---- defer-max softmax (all static indices)
    float lm0[4], lm1[4];
    #pragma unroll
    for (int rr=0;rr<4;rr++)
      lm1[rr] = fmaxf(fmaxf(s1m[0][rr], s1m[1][rr]), fmaxf(s1m[2][rr], s1m[3][rr]));
    if (act0)
      #pragma unroll
      for (int rr=0;rr<4;rr++)
        lm0[rr] = fmaxf(fmaxf(s0m[0][rr], s0m[1][rr]), fmaxf(s0m[2][rr], s0m[3][rr]));
    bool need = false;
    #pragma unroll
    for (int rr=0;rr<4;rr++) need = need || (lm1[rr] > m1r[rr] + 8.f);
    if (act0)
      #pragma unroll
      for (int rr=0;rr<4;rr++) need = need || (lm0[rr] > m0r[rr] + 8.f);
    if (__any(need)){
      #pragma unroll
      for (int rr=0;rr<4;rr++){
        float pmv = lm1[rr];
        #pragma unroll
        for (int off=1; off<16; off<<=1) pmv = fmaxf(pmv, __shfl_xor(pmv, off, 64));
        const float mnew = fmaxf(m1r[rr], pmv);
        const float corr = __expf(m1r[rr] - mnew);
        m1r[rr] = mnew;
        l1r[rr] *= corr;
        #pragma unroll
        for (int n=0;n<8;n++) o1[n][rr] *= corr;
      }
      if (act0){
        #pragma unroll
        for (int rr=0;rr<4;rr++){
          float pmv = lm0[rr];
          #pragma unroll
          for (int off=1; off<16; off<<=1) pmv = fmaxf(pmv, __shfl_xor(pmv, off, 64));
          const float mnew = fmaxf(m0r[rr], pmv);
          const float corr = __expf(m0r[rr] - mnew);
          m0r[rr] = mnew;
          l0r[rr] *= corr;
          #pragma unroll
          for (int n=0;n<8;n++) o0[n][rr] *= corr;
        }
      }
    }
    #pragma unroll
    for (int rr=0;rr<4;rr++){
      float s0 = 0.f;
      #pragma unroll
      for (int cc=0;cc<4;cc++){
        const float p = __expf(s1m[cc][rr] - m1r[rr]);
        s1m[cc][rr] = p;
        s0 += p;
      }
      #pragma unroll
      for (int off=1; off<16; off<<=1) s0 += __shfl_xor(s0, off, 64);
      l1r[rr] += s0;
    }
    if (act0){
      #pragma unroll
      for (int rr=0;rr<4;rr++){
        float s0 = 0.f;
        #pragma unroll
        for (int cc=0;cc<4;cc++){
          const float p = __expf(s0m[cc][rr] - m0r[rr]);
          s0m[cc][rr] = p;
          s0 += p;
        }
        #pragma unroll
        for (int off=1; off<16; off<<=1) s0 += __shfl_xor(s0, off, 64);
        l0r[rr] += s0;
      }
    }

    // ---- P -> LDS (static indices; frag1 -> rows 16..31, frag0 -> rows 0..15)
    #pragma unroll
    for (int cc=0;cc<4;cc++)
      #pragma unroll
      for (int rr=0;rr<4;rr++){
        const int qr = 16 + g4*4 + rr;
        Pl[wave][qr*64 + ((cc*16 + r16) ^ ((qr&7)<<3))] = f2bf(s1m[cc][rr]);
      }
    if (act0){
      #pragma unroll
      for (int cc=0;cc<4;cc++)
        #pragma unroll
        for (int rr=0;rr<4;rr++){
          const int qr = g4*4 + rr;
          Pl[wave][qr*64 + ((cc*16 + r16) ^ ((qr&7)<<3))] = f2bf(s0m[cc][rr]);
        }
    }
    asm volatile("s_waitcnt lgkmcnt(0)" ::: "memory");

    short8 pf0[2], pf1[2];
    {
      const int qr1 = 16 + r16;
      const int sw1 = (qr1 & 7) << 3;
      pf1[0] = *(const short8*)&Pl[wave][qr1*64 + ((g4*8)      ^ sw1)];
      pf1[1] = *(const short8*)&Pl[wave][qr1*64 + ((g4*8 + 32) ^ sw1)];
      if (act0){
        const int qr0 = r16;
        const int sw0 = (qr0 & 7) << 3;
        pf0[0] = *(const short8*)&Pl[wave][qr0*64 + ((g4*8)      ^ sw0)];
        pf0[1] = *(const short8*)&Pl[wave][qr0*64 + ((g4*8 + 32) ^ sw0)];
      }
    }
    #pragma unroll
    for (int n=0;n<8;n++){
      const int vr = n*16 + r16;
      const int sw = (vr & 7) << 3;
      short8 vf0 = *(const short8*)&Vl[cur][vr*64 + ((g4*8)      ^ sw)];
      short8 vf1 = *(const short8*)&Vl[cur][vr*64 + ((g4*8 + 32) ^ sw)];
      o1[n] = __builtin_amdgcn_mfma_f32_16x16x32_bf16(pf1[0], vf0, o1[n], 0,0,0);
      o1[n] = __builtin_amdgcn_mfma_f32_16x16x32_bf16(pf1[1], vf1, o1[n], 0,0,0);
      if (act0){
        o0[n] = __builtin_amdgcn_mfma_f32_16x16x32_bf16(pf0[0], vf0, o0[n], 0,0,0);
        o0[n] = __builtin_amdgcn_mfma_f32_16x16x32_bf16(pf0[1], vf1, o0[n], 0,0,0);
      }
    }
    cur ^= 1;
  }

  {
    const size_t yr0 = (size_t)(bb*T_SEQ + a*64 + wave*16 + g4*4) * C_DIM + h*128;
    #pragma unroll
    for (int n=0;n<8;n++)
      #pragma unroll
      for (int rr=0;rr<4;rr++){
        const float v = o0[n][rr] / l0r[rr];
        y[yr0 + (size_t)rr*C_DIM + n*16 + r16] = f2bf(v);
      }
  }
  {
    const size_t yr1 = (size_t)(bb*T_SEQ + bq*64 + wave*16 + g4*4) * C_DIM + h*128;
    #pragma unroll
    for (int n=0;n<8;n++)
      #pragma unroll
      for (int rr=0;rr<4;rr++){
        const float v = o1[n][rr] / l1r[rr];
        y[yr1 + (size_t)rr*C_DIM + n*16 + r16] = f2bf(v);
      }
  }
}

extern "C" void kernel_launch(void* const* d_in, const int* in_sizes, int n_in,
                              void* d_out, int out_size, void* d_ws, size_t ws_size,
                              hipStream_t stream){
  const float* x  = (const float*)d_in[0];
  const float* wa = (const float*)d_in[1];
  const float* wp = (const float*)d_in[2];
  float* out = (float*)d_out;

  u16* ws  = (u16*)d_ws;
  u16* xb  = ws;                 //  8,388,608 elems (x bf16) — reused as yb later
  u16* wab = xb  + 8388608;      // 12,582,912 elems (w_attn bf16)
  u16* wpb = wab + 12582912;     //  4,194,304 elems (w_proj bf16)
  u16* qk  = wpb + 4194304;      // 16,777,216 elems ([4096][4096] Q|K)
  u16* vt  = qk  + 16777216;     //  8,388,608 elems ([32][128][2048] V^T)
  u16* yb  = xb;                 // alias: x dead after GEMM1

  hipLaunchKernelGGL(cvt3_kernel, dim3(2048), dim3(256), 0, stream,
                     x, wa, wp, xb, wab, wpb);

  // qkv projection: grid 48 n-tiles(128) x 32 m-tiles(128) = 1536 = 3 rounds @ 2/CU
  hipLaunchKernelGGL((gemm256<1,u16>),   dim3(48,32), dim3(256), 0, stream,
                     xb, wab, qk, vt, 4096, 6144, 2048);
  hipLaunchKernelGGL(attn_kernel,        dim3(512),  dim3(256), 0, stream,
                     qk, vt, yb);
  // out projection: grid 16 x 32 = 512 = 1 round @ 2/CU
  hipLaunchKernelGGL((gemm256<0,float>), dim3(16,32), dim3(256), 0, stream,
                     yb, wpb, out, (u16*)nullptr, 4096, 2048, 2048);
}